// Round 3
// baseline (799.419 us; speedup 1.0000x reference)
//
#include <hip/hip_runtime.h>
#include <hip/hip_bf16.h>
#include <stdint.h>

typedef __bf16 bf16x8 __attribute__((ext_vector_type(8)));
typedef float  f32x4  __attribute__((ext_vector_type(4)));

#define DEV __device__ __forceinline__

constexpr int SUBJ  = 4;
constexpr int IN    = 4096;
constexpr int H     = 2048;
constexpr int DEPTH = 6;
constexpr int BATCH = 1024;
constexpr int BOT   = 128;
constexpr int IMG   = 768;
constexpr int TXT   = 768;
constexpr int MP    = 1408;   // padded sorted rows (worst case: 4 groups each padded to 128)
constexpr int MT    = 11;     // MP/128 row tiles

DEV float gelu_exact(float x){ return 0.5f*x*(1.0f + erff(x*0.70710678118654752440f)); }

DEV uint32_t pk_bf16(float a, float b){
  __hip_bfloat16 ha = __float2bfloat16(a), hb = __float2bfloat16(b);
  return (uint32_t)*reinterpret_cast<uint16_t*>(&ha)
       | ((uint32_t)*reinterpret_cast<uint16_t*>(&hb) << 16);
}

// ---------------- subject counting-sort (1 block, 1024 threads) ----------------
__global__ void sort_kernel(const int* __restrict__ ids, int* __restrict__ rowmap,
                            int* __restrict__ tileS){
  __shared__ int hist[16][4];
  __shared__ int basew[16][4];
  __shared__ int pstart[5];
  int tid = threadIdx.x;
  if (tid < MP) rowmap[tid] = -1;
  if (tid + 1024 < MP) rowmap[tid + 1024] = -1;
  int w = tid >> 6, lane = tid & 63;
  int my = ids[tid];
  unsigned long long mymask = 0ull;
  #pragma unroll
  for (int s = 0; s < 4; ++s){
    unsigned long long m = __ballot(my == s);
    if (lane == 0) hist[w][s] = (int)__popcll(m);
    if (s == my) mymask = m;
  }
  int myrank = (int)__popcll(mymask & ((1ull << lane) - 1ull));
  __syncthreads();
  if (tid == 0){
    for (int s = 0; s < 4; ++s){
      int run = 0;
      for (int ww = 0; ww < 16; ++ww){ basew[ww][s] = run; run += hist[ww][s]; }
      hist[0][s] = run;                               // total count of subject s
    }
    pstart[0] = 0;
    for (int s = 0; s < 4; ++s) pstart[s+1] = pstart[s] + ((hist[0][s] + 127) & ~127);
  }
  __syncthreads();
  int pos = pstart[my] + basew[w][my] + myrank;
  rowmap[pos] = tid;                                  // sorted pos -> original row
  if (tid < MT){
    int row0 = tid << 7, s = -1;
    for (int ss = 0; ss < 4; ++ss) if (row0 >= pstart[ss] && row0 < pstart[ss+1]) s = ss;
    tileS[tid] = s;                                   // subject per 128-row tile (-1 = inactive)
  }
}

// ---------------- gather voxels into sorted order, fp32 -> bf16 ----------------
__global__ void gather_voxels(const float* __restrict__ vox, const int* __restrict__ rowmap,
                              __hip_bfloat16* __restrict__ Vs){
  int r = blockIdx.x, tid = threadIdx.x;
  int orig = rowmap[r];
  #pragma unroll
  for (int i = 0; i < 4; ++i){
    int c = (i*256 + tid) << 2;
    float4 v = {0.f,0.f,0.f,0.f};
    if (orig >= 0) v = *reinterpret_cast<const float4*>(vox + (size_t)orig*IN + c);
    __hip_bfloat16 o[4] = {__float2bfloat16(v.x), __float2bfloat16(v.y),
                           __float2bfloat16(v.z), __float2bfloat16(v.w)};
    *reinterpret_cast<uint2*>(Vs + (size_t)r*IN + c) = *reinterpret_cast<const uint2*>(o);
  }
}

// ---------------- 128x128 tile MFMA GEMM ----------------
// A: bf16 [M][K] (sorted activations). B: fp32 [K][N] weight, converted+transposed
// into LDS on the fly (fused transpose, no pre-pass).
enum { EPI_ATOMIC = 0, EPI_RES_BF16 = 1, EPI_F32 = 2, EPI_HEAD = 3 };

template<int EPI>
__global__ __launch_bounds__(256, 2)
void gemm_bf16(const __hip_bfloat16* __restrict__ A, int lda,
               const float* __restrict__ Bw, int ldn, long long wsub,
               const int* __restrict__ tileS, const int* __restrict__ rowmap,
               int ksplit,
               const float* __restrict__ bias, int biassub,
               const float* __restrict__ resid, int ldres,
               float* __restrict__ outf, __hip_bfloat16* __restrict__ outb, int ldo)
{
  int mt = blockIdx.x, nt = blockIdx.y;
  int s = tileS[mt];
  if (s < 0) return;                       // inactive (pad) row tile
  const __hip_bfloat16* Ab = A + (size_t)mt*128*lda;
  const float* Bb = Bw + (size_t)s*wsub + (size_t)nt*128;   // column offset in [K][N]
  int kb = blockIdx.z * ksplit;
  int nk = ksplit >> 6;

  __shared__ __hip_bfloat16 sA[2][128*64];
  __shared__ __hip_bfloat16 sB[2][128*64];

  int tid = threadIdx.x;
  int lane = tid & 63;
  int wv = tid >> 6, wr = wv >> 1, wc = wv & 1;

  // B-staging thread mapping: thread owns 8 k-rows x 4 n-cols of the 64x128 tile
  int kq = tid >> 5;        // 0..7 -> k0 = 8*kq
  int nq = tid & 31;        // n0 = 4*nq
  int n4 = nq << 2;

  f32x4 acc[4][4];
  #pragma unroll
  for (int i = 0; i < 4; ++i)
    #pragma unroll
    for (int j = 0; j < 4; ++j) acc[i][j] = (f32x4){0.f,0.f,0.f,0.f};

  // A staging: global_load_lds 16B/lane, source pre-swizzled (cell ^ (row&7)).
  // 128 rows x 8 segments = 1024 cells -> 4 x 256 loads (i<4, NOT i<2!)
  auto stageA = [&](int buf, int k0){
    #pragma unroll
    for (int i = 0; i < 4; ++i){
      int cell = i*256 + tid;
      int row = cell >> 3, cc = cell & 7;
      int kg = k0 + ((cc ^ (row & 7)) << 3);
      __builtin_amdgcn_global_load_lds(
        (const __attribute__((address_space(1))) void*)(Ab + (size_t)row*lda + kg),
        (__attribute__((address_space(3))) void*)(&sA[buf][cell<<3]), 16, 0, 0);
    }
  };

  // B staging phase 1: issue 8 coalesced float4 loads (2 x 512B rows per wave-instr)
  auto stageB_load = [&](int k0g, float4* F){
    const float* p = Bb + (size_t)(k0g + (kq<<3))*ldn + n4;
    #pragma unroll
    for (int r = 0; r < 8; ++r)
      F[r] = *reinterpret_cast<const float4*>(p + (size_t)r*ldn);
  };
  // B staging phase 2: cvt to bf16 pairs, ds_write_b128 into swizzled [N][K] layout.
  // cell key = ((n>>3)^n)&7 -> both writes and fragment reads spread over 32 banks.
  auto stageB_write = [&](int buf, const float4* F){
    #pragma unroll
    for (int j = 0; j < 4; ++j){
      int n = n4 + j;
      int cell = (kq ^ (n >> 3) ^ n) & 7;
      uint4 d;
      d.x = pk_bf16(((const float*)&F[0])[j], ((const float*)&F[1])[j]);
      d.y = pk_bf16(((const float*)&F[2])[j], ((const float*)&F[3])[j]);
      d.z = pk_bf16(((const float*)&F[4])[j], ((const float*)&F[5])[j]);
      d.w = pk_bf16(((const float*)&F[6])[j], ((const float*)&F[7])[j]);
      *reinterpret_cast<uint4*>(&sB[buf][(n<<6) + (cell<<3)]) = d;
    }
  };

  float4 F[8];
  stageB_load(kb, F);
  stageA(0, kb);
  stageB_write(0, F);
  __syncthreads();

  for (int t = 0; t < nk; ++t){
    if (t+1 < nk){
      stageB_load(kb + ((t+1)<<6), F);     // issue early: latency hides under MFMA
      stageA((t+1)&1, kb + ((t+1)<<6));
    }
    const char* baseA = (const char*)(&sA[t&1][0]);
    const char* baseB = (const char*)(&sB[t&1][0]);
    int rA = (wr<<6) + (lane & 15);
    int rB = (wc<<6) + (lane & 15);
    #pragma unroll
    for (int kk = 0; kk < 2; ++kk){
      int koffA = ((((kk<<5) + ((lane>>4)<<3)) << 1)) ^ ((lane & 7) << 4);
      bf16x8 av[4], bv[4];
      #pragma unroll
      for (int f = 0; f < 4; ++f){
        int rowA = rA + f*16;
        av[f] = *reinterpret_cast<const bf16x8*>(baseA + (size_t)rowA*128 + koffA);
        int rowB = rB + f*16;
        int cellB = (((kk<<2) + (lane>>4)) ^ (rowB >> 3) ^ rowB) & 7;
        bv[f] = *reinterpret_cast<const bf16x8*>(baseB + (size_t)rowB*128 + (cellB<<4));
      }
      #pragma unroll
      for (int i = 0; i < 4; ++i)
        #pragma unroll
        for (int j = 0; j < 4; ++j)
          acc[i][j] = __builtin_amdgcn_mfma_f32_16x16x32_bf16(av[i], bv[j], acc[i][j], 0, 0, 0);
    }
    if (t+1 < nk) stageB_write((t+1)&1, F);
    __syncthreads();
  }

  // epilogue; C/D layout (m89-verified): col = lane&15, row = (lane>>4)*4 + reg
  #pragma unroll
  for (int i = 0; i < 4; ++i){
    int rbase = (mt<<7) + (wr<<6) + (i<<4) + ((lane>>4)<<2);
    #pragma unroll
    for (int j = 0; j < 4; ++j){
      int col = (nt<<7) + (wc<<6) + (j<<4) + (lane & 15);
      #pragma unroll
      for (int q = 0; q < 4; ++q){
        int r = rbase + q;
        float v = acc[i][j][q];
        if constexpr (EPI == EPI_ATOMIC){
          atomicAdd(outf + (size_t)r*ldo + col, v);
        } else if constexpr (EPI == EPI_RES_BF16){
          int orig = rowmap[r];
          if (orig >= 0){
            v += bias[(size_t)s*biassub + col] + resid[(size_t)orig*ldres + col];
            outb[(size_t)r*ldo + col] = __float2bfloat16(v);
          }
        } else if constexpr (EPI == EPI_F32){
          outf[(size_t)r*ldo + col] = v + bias[(size_t)s*biassub + col];
        } else { // EPI_HEAD: scatter back to original row order
          int orig = rowmap[r];
          if (orig >= 0) outf[(size_t)orig*ldo + col] = v + bias[col];
        }
      }
    }
  }
}

// ---------------- T1 = gelu(T1acc + db[s])  (bf16) ----------------
__global__ void t1_epilogue(const float* __restrict__ acc, const float* __restrict__ db,
                            const int* __restrict__ rowmap, const int* __restrict__ tileS,
                            __hip_bfloat16* __restrict__ T1){
  int idx = blockIdx.x*256 + threadIdx.x;
  int r = idx >> 7, c = idx & 127;
  float v = 0.f;
  if (rowmap[r] >= 0){
    int s = tileS[r >> 7];
    v = gelu_exact(acc[idx] + db[s*BOT + c]);
  }
  T1[idx] = __float2bfloat16(v);
}

// ---------------- row LayerNorm + gelu (+optional residual), writes fp32 X and bf16 X ----
template<int RES>
__global__ void ln_gelu_kernel(const float* __restrict__ Z, const float* __restrict__ g,
                               const float* __restrict__ b, int gsub,
                               const int* __restrict__ tileS, const int* __restrict__ rowmap,
                               float* __restrict__ Xf, __hip_bfloat16* __restrict__ Xb){
  int r = blockIdx.x, tid = threadIdx.x;
  size_t rowoff = (size_t)r * H;
  int c0 = tid << 3;
  int orig = rowmap[r];
  if (orig < 0){
    float4 zf = {0.f,0.f,0.f,0.f};
    *reinterpret_cast<float4*>(Xf + rowoff + c0)     = zf;
    *reinterpret_cast<float4*>(Xf + rowoff + c0 + 4) = zf;
    uint4 zu = {0u,0u,0u,0u};
    *reinterpret_cast<uint4*>(Xb + rowoff + c0) = zu;
    return;
  }
  float z[8];
  float4 v1 = *reinterpret_cast<const float4*>(Z + rowoff + c0);
  float4 v2 = *reinterpret_cast<const float4*>(Z + rowoff + c0 + 4);
  z[0]=v1.x; z[1]=v1.y; z[2]=v1.z; z[3]=v1.w;
  z[4]=v2.x; z[5]=v2.y; z[6]=v2.z; z[7]=v2.w;
  float s1 = 0.f, s2 = 0.f;
  #pragma unroll
  for (int j = 0; j < 8; ++j){ s1 += z[j]; s2 += z[j]*z[j]; }
  #pragma unroll
  for (int m = 32; m >= 1; m >>= 1){ s1 += __shfl_xor(s1, m); s2 += __shfl_xor(s2, m); }
  __shared__ float red[4][2];
  int wv = tid >> 6, lane = tid & 63;
  if (lane == 0){ red[wv][0] = s1; red[wv][1] = s2; }
  __syncthreads();
  s1 = red[0][0]+red[1][0]+red[2][0]+red[3][0];
  s2 = red[0][1]+red[1][1]+red[2][1]+red[3][1];
  const float invH = 1.f / (float)H;
  float mu  = s1 * invH;
  float var = s2 * invH - mu*mu;
  float rs  = rsqrtf(var + 1e-5f);
  int si = gsub ? tileS[r>>7] : 0;
  const float* gp = g + (size_t)si*gsub;
  const float* bp = b + (size_t)si*gsub;
  float o[8];
  #pragma unroll
  for (int j = 0; j < 8; ++j){
    float t = (z[j]-mu)*rs*gp[c0+j] + bp[c0+j];
    o[j] = gelu_exact(t);
  }
  if constexpr (RES){
    float4 x1 = *reinterpret_cast<const float4*>(Xf + rowoff + c0);
    float4 x2 = *reinterpret_cast<const float4*>(Xf + rowoff + c0 + 4);
    o[0]+=x1.x; o[1]+=x1.y; o[2]+=x1.z; o[3]+=x1.w;
    o[4]+=x2.x; o[5]+=x2.y; o[6]+=x2.z; o[7]+=x2.w;
  }
  float4 w1 = {o[0],o[1],o[2],o[3]}, w2 = {o[4],o[5],o[6],o[7]};
  *reinterpret_cast<float4*>(Xf + rowoff + c0)     = w1;
  *reinterpret_cast<float4*>(Xf + rowoff + c0 + 4) = w2;
  __hip_bfloat16 ob[8];
  #pragma unroll
  for (int j = 0; j < 8; ++j) ob[j] = __float2bfloat16(o[j]);
  *reinterpret_cast<uint4*>(Xb + rowoff + c0) = *reinterpret_cast<const uint4*>(ob);
}

// ------------------------------------------------------------------------------
extern "C" void kernel_launch(void* const* d_in, const int* in_sizes, int n_in,
                              void* d_out, int out_size, void* d_ws, size_t ws_size,
                              hipStream_t stream){
  (void)in_sizes; (void)n_in; (void)out_size; (void)ws_size;
  const float* vox       = (const float*)d_in[0];
  const int*   ids       = (const int*)  d_in[1];
  const float* ad_down_w = (const float*)d_in[2];
  const float* ad_down_b = (const float*)d_in[3];
  const float* ad_up_w   = (const float*)d_in[4];
  const float* ad_up_b   = (const float*)d_in[5];
  const float* enc_w     = (const float*)d_in[6];
  const float* enc_b     = (const float*)d_in[7];
  const float* enc_ln_g  = (const float*)d_in[8];
  const float* enc_ln_bb = (const float*)d_in[9];
  const float* bb_w      = (const float*)d_in[10];
  const float* bb_b      = (const float*)d_in[11];
  const float* bb_ln_g   = (const float*)d_in[12];
  const float* bb_ln_b   = (const float*)d_in[13];
  const float* img_w     = (const float*)d_in[14];
  const float* img_b     = (const float*)d_in[15];
  const float* txt_w     = (const float*)d_in[16];
  const float* txt_b     = (const float*)d_in[17];
  float* out = (float*)d_out;

  char* wp = (char*)d_ws;
  auto alloc = [&](size_t bytes)->char*{ char* p = wp; wp += (bytes + 255) & ~(size_t)255; return p; };
  int* rowmap = (int*)alloc(MP * sizeof(int));
  int* tileS  = (int*)alloc(MT * sizeof(int));
  __hip_bfloat16* Vs    = (__hip_bfloat16*)alloc((size_t)MP*IN*2);
  float* T1acc          = (float*)alloc((size_t)MP*BOT*4);
  __hip_bfloat16* T1    = (__hip_bfloat16*)alloc((size_t)MP*BOT*2);
  __hip_bfloat16* Hs    = (__hip_bfloat16*)alloc((size_t)MP*IN*2);
  float* Z              = (float*)alloc((size_t)MP*H*4);
  float* Xf             = (float*)alloc((size_t)MP*H*4);
  __hip_bfloat16* Xb    = (__hip_bfloat16*)alloc((size_t)MP*H*2);

  sort_kernel<<<1, 1024, 0, stream>>>(ids, rowmap, tileS);
  gather_voxels<<<MP, 256, 0, stream>>>(vox, rowmap, Vs);
  hipMemsetAsync(T1acc, 0, (size_t)MP*BOT*4, stream);

  // K1: adapter down (split-K=8, atomic fp32 accum), then gelu+bias -> bf16
  gemm_bf16<EPI_ATOMIC><<<dim3(MT,1,8), 256, 0, stream>>>(
      Vs, IN, ad_down_w, BOT, (long long)IN*BOT, tileS, rowmap, IN/8,
      nullptr, 0, nullptr, 0, T1acc, nullptr, BOT);
  t1_epilogue<<<MP*BOT/256, 256, 0, stream>>>(T1acc, ad_down_b, rowmap, tileS, T1);

  // K2: adapter up + voxel residual + bias -> bf16 Hs
  gemm_bf16<EPI_RES_BF16><<<dim3(MT, IN/128, 1), 256, 0, stream>>>(
      T1, BOT, ad_up_w, IN, (long long)IN*BOT, tileS, rowmap, BOT,
      ad_up_b, IN, vox, IN, nullptr, Hs, IN);

  // K3: encoder linear -> fp32 Z, then LN+gelu -> Xf/Xb
  gemm_bf16<EPI_F32><<<dim3(MT, H/128, 1), 256, 0, stream>>>(
      Hs, IN, enc_w, H, (long long)IN*H, tileS, rowmap, IN,
      enc_b, H, nullptr, 0, Z, nullptr, H);
  ln_gelu_kernel<0><<<MP, 256, 0, stream>>>(Z, enc_ln_g, enc_ln_bb, H, tileS, rowmap, Xf, Xb);

  // backbone: 6 x (linear -> Z; X += gelu(ln(Z)))
  for (int d = 0; d < DEPTH; ++d){
    gemm_bf16<EPI_F32><<<dim3(MT, H/128, 1), 256, 0, stream>>>(
        Xb, H, bb_w + (size_t)d*H*H, H, 0, tileS, rowmap, H,
        bb_b + (size_t)d*H, 0, nullptr, 0, Z, nullptr, H);
    ln_gelu_kernel<1><<<MP, 256, 0, stream>>>(Z, bb_ln_g + (size_t)d*H, bb_ln_b + (size_t)d*H,
                                              0, tileS, rowmap, Xf, Xb);
  }

  // heads: scatter rows back to original order
  gemm_bf16<EPI_HEAD><<<dim3(MT, IMG/128, 1), 256, 0, stream>>>(
      Xb, H, img_w, IMG, 0, tileS, rowmap, H,
      img_b, 0, nullptr, 0, out, nullptr, IMG);
  gemm_bf16<EPI_HEAD><<<dim3(MT, TXT/128, 1), 256, 0, stream>>>(
      Xb, H, txt_w, TXT, 0, tileS, rowmap, H,
      txt_b, 0, nullptr, 0, out + (size_t)BATCH*IMG, nullptr, TXT);
}

// Round 4
// 607.490 us; speedup vs baseline: 1.3159x; 1.3159x over previous
//
#include <hip/hip_runtime.h>
#include <hip/hip_bf16.h>
#include <stdint.h>

typedef __bf16 bf16x8 __attribute__((ext_vector_type(8)));
typedef float  f32x4  __attribute__((ext_vector_type(4)));

#define DEV __device__ __forceinline__

constexpr int SUBJ  = 4;
constexpr int IN    = 4096;
constexpr int H     = 2048;
constexpr int DEPTH = 6;
constexpr int BATCH = 1024;
constexpr int BOT   = 128;
constexpr int IMG   = 768;
constexpr int TXT   = 768;
constexpr int MP    = 1408;   // padded sorted rows
constexpr int MT    = 11;     // MP/128 row tiles

DEV float gelu_exact(float x){ return 0.5f*x*(1.0f + erff(x*0.70710678118654752440f)); }

DEV uint32_t pk_bf16(float a, float b){
  __hip_bfloat16 ha = __float2bfloat16(a), hb = __float2bfloat16(b);
  return (uint32_t)*reinterpret_cast<uint16_t*>(&ha)
       | ((uint32_t)*reinterpret_cast<uint16_t*>(&hb) << 16);
}

// ---------------- subject counting-sort (1 block, 1024 threads) ----------------
__global__ void sort_kernel(const int* __restrict__ ids, int* __restrict__ rowmap,
                            int* __restrict__ tileS){
  __shared__ int hist[16][4];
  __shared__ int basew[16][4];
  __shared__ int pstart[5];
  int tid = threadIdx.x;
  if (tid < MP) rowmap[tid] = -1;
  if (tid + 1024 < MP) rowmap[tid + 1024] = -1;
  int w = tid >> 6, lane = tid & 63;
  int my = ids[tid];
  unsigned long long mymask = 0ull;
  #pragma unroll
  for (int s = 0; s < 4; ++s){
    unsigned long long m = __ballot(my == s);
    if (lane == 0) hist[w][s] = (int)__popcll(m);
    if (s == my) mymask = m;
  }
  int myrank = (int)__popcll(mymask & ((1ull << lane) - 1ull));
  __syncthreads();
  if (tid == 0){
    for (int s = 0; s < 4; ++s){
      int run = 0;
      for (int ww = 0; ww < 16; ++ww){ basew[ww][s] = run; run += hist[ww][s]; }
      hist[0][s] = run;
    }
    pstart[0] = 0;
    for (int s = 0; s < 4; ++s) pstart[s+1] = pstart[s] + ((hist[0][s] + 127) & ~127);
  }
  __syncthreads();
  int pos = pstart[my] + basew[w][my] + myrank;
  rowmap[pos] = tid;
  if (tid < MT){
    int row0 = tid << 7, s = -1;
    for (int ss = 0; ss < 4; ++ss) if (row0 >= pstart[ss] && row0 < pstart[ss+1]) s = ss;
    tileS[tid] = s;
  }
}

// ---------------- gather voxels into sorted order, fp32 -> bf16 ----------------
__global__ void gather_voxels(const float* __restrict__ vox, const int* __restrict__ rowmap,
                              __hip_bfloat16* __restrict__ Vs){
  int r = blockIdx.x, tid = threadIdx.x;
  int orig = rowmap[r];
  #pragma unroll
  for (int i = 0; i < 4; ++i){
    int c = (i*256 + tid) << 2;
    float4 v = {0.f,0.f,0.f,0.f};
    if (orig >= 0) v = *reinterpret_cast<const float4*>(vox + (size_t)orig*IN + c);
    __hip_bfloat16 o[4] = {__float2bfloat16(v.x), __float2bfloat16(v.y),
                           __float2bfloat16(v.z), __float2bfloat16(v.w)};
    *reinterpret_cast<uint2*>(Vs + (size_t)r*IN + c) = *reinterpret_cast<const uint2*>(o);
  }
}

// ---------------- 128x128 tile MFMA GEMM, fused fp32->bf16 B transpose ----------------
// Grid: MT*NT*KZ blocks, XCD-swizzled decode: all blocks sharing one (nt,kz) B-panel
// land on ONE XCD (ids differ by 8) so the fp32 panel is read once into its L2.
// Requires NT*KZ % 8 == 0.
enum { EPI_ATOMIC = 0, EPI_RES_BF16 = 1, EPI_HEADS = 3 };

template<int EPI>
__global__ __launch_bounds__(256, 2)
void gemm_bf16(const __hip_bfloat16* __restrict__ A, int lda,
               const float* __restrict__ Bw, int ldn, long long wsub,
               const int* __restrict__ tileS, const int* __restrict__ rowmap,
               int NT, int ksplit,
               const float* __restrict__ bias, int biassub,
               const float* __restrict__ resid, int ldres,
               float* __restrict__ outf, __hip_bfloat16* __restrict__ outb, int ldo,
               const float* __restrict__ Bw2, const float* __restrict__ bias2,
               float* __restrict__ outf2)
{
  // XCD-aware decode: b = q*(8*MT) + mt*8 + (g%8);  g = q*8 + (b&7)
  int b   = blockIdx.x;
  int glo = b & 7;
  int rem = b % (8*MT);
  int mt  = rem >> 3;
  int g   = (b / (8*MT)) * 8 + glo;
  int nt  = g % NT;
  int kzi = g / NT;

  int s = tileS[mt];
  if (s < 0) return;                       // inactive (pad) row tile
  const __hip_bfloat16* Ab = A + (size_t)mt*128*lda;

  const float* Bb;
  const float* hbias = nullptr; float* hout = nullptr; int ntl = nt;
  if constexpr (EPI == EPI_HEADS){
    int half = NT >> 1;
    if (nt < half){ Bb = Bw  + (size_t)nt*128;        hbias = bias;  hout = outf;  ntl = nt; }
    else          { Bb = Bw2 + (size_t)(nt-half)*128; hbias = bias2; hout = outf2; ntl = nt-half; }
  } else {
    Bb = Bw + (size_t)s*wsub + (size_t)nt*128;
  }

  int kb = kzi * ksplit;
  int nk = ksplit >> 6;

  __shared__ __hip_bfloat16 sA[2][128*64];
  __shared__ __hip_bfloat16 sB[2][128*64];

  int tid = threadIdx.x;
  int lane = tid & 63;
  int wv = tid >> 6, wr = wv >> 1, wc = wv & 1;

  // B-staging thread mapping: thread owns 8 k-rows x 4 n-cols of the 64x128 tile
  int kq = tid >> 5;
  int nq = tid & 31;
  int n4 = nq << 2;

  f32x4 acc[4][4];
  #pragma unroll
  for (int i = 0; i < 4; ++i)
    #pragma unroll
    for (int j = 0; j < 4; ++j) acc[i][j] = (f32x4){0.f,0.f,0.f,0.f};

  auto stageA = [&](int buf, int k0){
    #pragma unroll
    for (int i = 0; i < 4; ++i){
      int cell = i*256 + tid;
      int row = cell >> 3, cc = cell & 7;
      int kg = k0 + ((cc ^ (row & 7)) << 3);
      __builtin_amdgcn_global_load_lds(
        (const __attribute__((address_space(1))) void*)(Ab + (size_t)row*lda + kg),
        (__attribute__((address_space(3))) void*)(&sA[buf][cell<<3]), 16, 0, 0);
    }
  };

  auto stageB_load = [&](int k0g, float4* F){
    const float* p = Bb + (size_t)(k0g + (kq<<3))*ldn + n4;
    #pragma unroll
    for (int r = 0; r < 8; ++r)
      F[r] = *reinterpret_cast<const float4*>(p + (size_t)r*ldn);
  };
  auto stageB_write = [&](int buf, const float4* F){
    #pragma unroll
    for (int j = 0; j < 4; ++j){
      int n = n4 + j;
      int cell = (kq ^ (n >> 3) ^ n) & 7;
      uint4 d;
      d.x = pk_bf16(((const float*)&F[0])[j], ((const float*)&F[1])[j]);
      d.y = pk_bf16(((const float*)&F[2])[j], ((const float*)&F[3])[j]);
      d.z = pk_bf16(((const float*)&F[4])[j], ((const float*)&F[5])[j]);
      d.w = pk_bf16(((const float*)&F[6])[j], ((const float*)&F[7])[j]);
      *reinterpret_cast<uint4*>(&sB[buf][(n<<6) + (cell<<3)]) = d;
    }
  };

  float4 F[8];
  stageB_load(kb, F);
  stageA(0, kb);
  stageB_write(0, F);
  __syncthreads();

  for (int t = 0; t < nk; ++t){
    if (t+1 < nk){
      stageB_load(kb + ((t+1)<<6), F);     // issue early: latency hides under MFMA
      stageA((t+1)&1, kb + ((t+1)<<6));
    }
    const char* baseA = (const char*)(&sA[t&1][0]);
    const char* baseB = (const char*)(&sB[t&1][0]);
    int rA = (wr<<6) + (lane & 15);
    int rB = (wc<<6) + (lane & 15);
    #pragma unroll
    for (int kk = 0; kk < 2; ++kk){
      int koffA = ((((kk<<5) + ((lane>>4)<<3)) << 1)) ^ ((lane & 7) << 4);
      bf16x8 av[4], bv[4];
      #pragma unroll
      for (int f = 0; f < 4; ++f){
        int rowA = rA + f*16;
        av[f] = *reinterpret_cast<const bf16x8*>(baseA + (size_t)rowA*128 + koffA);
        int rowB = rB + f*16;
        int cellB = (((kk<<2) + (lane>>4)) ^ (rowB >> 3) ^ rowB) & 7;
        bv[f] = *reinterpret_cast<const bf16x8*>(baseB + (size_t)rowB*128 + (cellB<<4));
      }
      #pragma unroll
      for (int i = 0; i < 4; ++i)
        #pragma unroll
        for (int j = 0; j < 4; ++j)
          acc[i][j] = __builtin_amdgcn_mfma_f32_16x16x32_bf16(av[i], bv[j], acc[i][j], 0, 0, 0);
    }
    if (t+1 < nk) stageB_write((t+1)&1, F);
    __syncthreads();
  }

  // epilogue; C/D layout (m89-verified): col = lane&15, row = (lane>>4)*4 + reg
  #pragma unroll
  for (int i = 0; i < 4; ++i){
    int rbase = (mt<<7) + (wr<<6) + (i<<4) + ((lane>>4)<<2);
    #pragma unroll
    for (int j = 0; j < 4; ++j){
      int colp = (wc<<6) + (j<<4) + (lane & 15);     // col within 128-tile
      #pragma unroll
      for (int q = 0; q < 4; ++q){
        int r = rbase + q;
        float v = acc[i][j][q];
        if constexpr (EPI == EPI_ATOMIC){
          int col = (nt<<7) + colp;
          atomicAdd(outf + (size_t)r*ldo + col, v);
        } else if constexpr (EPI == EPI_RES_BF16){
          int col = (nt<<7) + colp;
          int orig = rowmap[r];
          if (orig >= 0){
            v += bias[(size_t)s*biassub + col] + resid[(size_t)orig*ldres + col];
            outb[(size_t)r*ldo + col] = __float2bfloat16(v);
          }
        } else { // EPI_HEADS: atomic scatter to original rows, bias added by kzi==0 slice
          int col = (ntl<<7) + colp;
          int orig = rowmap[r];
          if (orig >= 0){
            float vv = v + (kzi == 0 ? hbias[col] : 0.f);
            atomicAdd(hout + (size_t)orig*ldo + col, vv);
          }
        }
      }
    }
  }
}

// ---------------- T1 = gelu(T1acc + db[s])  (bf16) ----------------
__global__ void t1_epilogue(const float* __restrict__ acc, const float* __restrict__ db,
                            const int* __restrict__ rowmap, const int* __restrict__ tileS,
                            __hip_bfloat16* __restrict__ T1){
  int idx = blockIdx.x*256 + threadIdx.x;
  int r = idx >> 7, c = idx & 127;
  float v = 0.f;
  if (rowmap[r] >= 0){
    int s = tileS[r >> 7];
    v = gelu_exact(acc[idx] + db[s*BOT + c]);
  }
  T1[idx] = __float2bfloat16(v);
}

// ---------------- row LN(+linear bias) + gelu (+residual), fp32 Xf + bf16 Xb ----------
// Z holds x@W (no bias); lb is the linear bias, added BEFORE mean/var (exact).
template<int RES>
__global__ void ln_gelu_kernel(const float* __restrict__ Z, const float* __restrict__ g,
                               const float* __restrict__ b, int gsub,
                               const float* __restrict__ lb,
                               const int* __restrict__ tileS, const int* __restrict__ rowmap,
                               float* __restrict__ Xf, __hip_bfloat16* __restrict__ Xb){
  int r = blockIdx.x, tid = threadIdx.x;
  size_t rowoff = (size_t)r * H;
  int c0 = tid << 3;
  int orig = rowmap[r];
  if (orig < 0){
    float4 zf = {0.f,0.f,0.f,0.f};
    *reinterpret_cast<float4*>(Xf + rowoff + c0)     = zf;
    *reinterpret_cast<float4*>(Xf + rowoff + c0 + 4) = zf;
    uint4 zu = {0u,0u,0u,0u};
    *reinterpret_cast<uint4*>(Xb + rowoff + c0) = zu;
    return;
  }
  int si = gsub ? tileS[r>>7] : 0;
  const float* gp  = g  + (size_t)si*gsub;
  const float* bp  = b  + (size_t)si*gsub;
  const float* lbp = lb + (size_t)si*gsub;
  float z[8];
  float4 v1 = *reinterpret_cast<const float4*>(Z + rowoff + c0);
  float4 v2 = *reinterpret_cast<const float4*>(Z + rowoff + c0 + 4);
  z[0]=v1.x; z[1]=v1.y; z[2]=v1.z; z[3]=v1.w;
  z[4]=v2.x; z[5]=v2.y; z[6]=v2.z; z[7]=v2.w;
  #pragma unroll
  for (int j = 0; j < 8; ++j) z[j] += lbp[c0+j];
  float s1 = 0.f, s2 = 0.f;
  #pragma unroll
  for (int j = 0; j < 8; ++j){ s1 += z[j]; s2 += z[j]*z[j]; }
  #pragma unroll
  for (int m = 32; m >= 1; m >>= 1){ s1 += __shfl_xor(s1, m); s2 += __shfl_xor(s2, m); }
  __shared__ float red[4][2];
  int wv = tid >> 6, lane = tid & 63;
  if (lane == 0){ red[wv][0] = s1; red[wv][1] = s2; }
  __syncthreads();
  s1 = red[0][0]+red[1][0]+red[2][0]+red[3][0];
  s2 = red[0][1]+red[1][1]+red[2][1]+red[3][1];
  const float invH = 1.f / (float)H;
  float mu  = s1 * invH;
  float var = s2 * invH - mu*mu;
  float rs  = rsqrtf(var + 1e-5f);
  float o[8];
  #pragma unroll
  for (int j = 0; j < 8; ++j){
    float t = (z[j]-mu)*rs*gp[c0+j] + bp[c0+j];
    o[j] = gelu_exact(t);
  }
  if constexpr (RES){
    float4 x1 = *reinterpret_cast<const float4*>(Xf + rowoff + c0);
    float4 x2 = *reinterpret_cast<const float4*>(Xf + rowoff + c0 + 4);
    o[0]+=x1.x; o[1]+=x1.y; o[2]+=x1.z; o[3]+=x1.w;
    o[4]+=x2.x; o[5]+=x2.y; o[6]+=x2.z; o[7]+=x2.w;
  }
  float4 w1 = {o[0],o[1],o[2],o[3]}, w2 = {o[4],o[5],o[6],o[7]};
  *reinterpret_cast<float4*>(Xf + rowoff + c0)     = w1;
  *reinterpret_cast<float4*>(Xf + rowoff + c0 + 4) = w2;
  __hip_bfloat16 ob[8];
  #pragma unroll
  for (int j = 0; j < 8; ++j) ob[j] = __float2bfloat16(o[j]);
  *reinterpret_cast<uint4*>(Xb + rowoff + c0) = *reinterpret_cast<const uint4*>(ob);
}

// ------------------------------------------------------------------------------
extern "C" void kernel_launch(void* const* d_in, const int* in_sizes, int n_in,
                              void* d_out, int out_size, void* d_ws, size_t ws_size,
                              hipStream_t stream){
  (void)in_sizes; (void)n_in; (void)out_size; (void)ws_size;
  const float* vox       = (const float*)d_in[0];
  const int*   ids       = (const int*)  d_in[1];
  const float* ad_down_w = (const float*)d_in[2];
  const float* ad_down_b = (const float*)d_in[3];
  const float* ad_up_w   = (const float*)d_in[4];
  const float* ad_up_b   = (const float*)d_in[5];
  const float* enc_w     = (const float*)d_in[6];
  const float* enc_b     = (const float*)d_in[7];
  const float* enc_ln_g  = (const float*)d_in[8];
  const float* enc_ln_bb = (const float*)d_in[9];
  const float* bb_w      = (const float*)d_in[10];
  const float* bb_b      = (const float*)d_in[11];
  const float* bb_ln_g   = (const float*)d_in[12];
  const float* bb_ln_b   = (const float*)d_in[13];
  const float* img_w     = (const float*)d_in[14];
  const float* img_b     = (const float*)d_in[15];
  const float* txt_w     = (const float*)d_in[16];
  const float* txt_b     = (const float*)d_in[17];
  float* out = (float*)d_out;

  char* wp = (char*)d_ws;
  auto alloc = [&](size_t bytes)->char*{ char* p = wp; wp += (bytes + 255) & ~(size_t)255; return p; };
  int* rowmap = (int*)alloc(MP * sizeof(int));
  int* tileS  = (int*)alloc(MT * sizeof(int));
  __hip_bfloat16* Vs    = (__hip_bfloat16*)alloc((size_t)MP*IN*2);
  float* T1acc          = (float*)alloc((size_t)MP*BOT*4);
  __hip_bfloat16* T1    = (__hip_bfloat16*)alloc((size_t)MP*BOT*2);
  __hip_bfloat16* Hs    = (__hip_bfloat16*)alloc((size_t)MP*IN*2);
  float* Z              = (float*)alloc((size_t)MP*H*4);
  float* Xf             = (float*)alloc((size_t)MP*H*4);
  __hip_bfloat16* Xb    = (__hip_bfloat16*)alloc((size_t)MP*H*2);

  sort_kernel<<<1, 1024, 0, stream>>>(ids, rowmap, tileS);
  gather_voxels<<<MP, 256, 0, stream>>>(vox, rowmap, Vs);
  hipMemsetAsync(T1acc, 0, (size_t)MP*BOT*4, stream);

  // K1: adapter down, NT=1, KZ=8 (ksplit=512), atomic into T1acc
  gemm_bf16<EPI_ATOMIC><<<MT*1*8, 256, 0, stream>>>(
      Vs, IN, ad_down_w, BOT, (long long)IN*BOT, tileS, rowmap, 1, 512,
      nullptr, 0, nullptr, 0, T1acc, nullptr, BOT, nullptr, nullptr, nullptr);
  t1_epilogue<<<MP*BOT/256, 256, 0, stream>>>(T1acc, ad_down_b, rowmap, tileS, T1);

  // K2: adapter up + residual, NT=32, KZ=1 (ksplit=128) -> bf16 Hs
  gemm_bf16<EPI_RES_BF16><<<MT*32*1, 256, 0, stream>>>(
      T1, BOT, ad_up_w, IN, (long long)BOT*IN, tileS, rowmap, 32, 128,
      ad_up_b, IN, vox, IN, nullptr, Hs, IN, nullptr, nullptr, nullptr);

  // K3: encoder linear, NT=16, KZ=2 (ksplit=2048), atomic into zeroed Z; bias in LN
  hipMemsetAsync(Z, 0, (size_t)MP*H*4, stream);
  gemm_bf16<EPI_ATOMIC><<<MT*16*2, 256, 0, stream>>>(
      Hs, IN, enc_w, H, (long long)IN*H, tileS, rowmap, 16, 2048,
      nullptr, 0, nullptr, 0, Z, nullptr, H, nullptr, nullptr, nullptr);
  ln_gelu_kernel<0><<<MP, 256, 0, stream>>>(Z, enc_ln_g, enc_ln_bb, H, enc_b,
                                            tileS, rowmap, Xf, Xb);

  // backbone: 6 x (memset Z; linear atomic; X += gelu(ln(Z + b)))
  for (int d = 0; d < DEPTH; ++d){
    hipMemsetAsync(Z, 0, (size_t)MP*H*4, stream);
    gemm_bf16<EPI_ATOMIC><<<MT*16*2, 256, 0, stream>>>(
        Xb, H, bb_w + (size_t)d*H*H, H, 0, tileS, rowmap, 16, 1024,
        nullptr, 0, nullptr, 0, Z, nullptr, H, nullptr, nullptr, nullptr);
    ln_gelu_kernel<1><<<MP, 256, 0, stream>>>(Z, bb_ln_g + (size_t)d*H, bb_ln_b + (size_t)d*H,
                                              0, bb_b + (size_t)d*H, tileS, rowmap, Xf, Xb);
  }

  // heads: ONE dispatch (img cols 0..5, txt cols 6..11), NT=12, KZ=2, atomic scatter
  hipMemsetAsync(out, 0, (size_t)BATCH*(IMG+TXT)*4, stream);
  gemm_bf16<EPI_HEADS><<<MT*12*2, 256, 0, stream>>>(
      Xb, H, img_w, IMG, 0, tileS, rowmap, 12, 1024,
      img_b, 0, nullptr, 0, out, nullptr, IMG,
      txt_w, txt_b, out + (size_t)BATCH*IMG);
}

// Round 5
// 497.462 us; speedup vs baseline: 1.6070x; 1.2212x over previous
//
#include <hip/hip_runtime.h>
#include <hip/hip_bf16.h>
#include <stdint.h>

typedef __bf16 bf16x8 __attribute__((ext_vector_type(8)));
typedef float  f32x4  __attribute__((ext_vector_type(4)));

#define DEV __device__ __forceinline__

constexpr int SUBJ  = 4;
constexpr int IN    = 4096;
constexpr int H     = 2048;
constexpr int DEPTH = 6;
constexpr int BATCH = 1024;
constexpr int BOT   = 128;
constexpr int IMG   = 768;
constexpr int TXT   = 768;
constexpr int MP    = 1408;   // padded sorted rows
constexpr int MT    = 11;     // MP/128 row tiles

DEV float gelu_exact(float x){ return 0.5f*x*(1.0f + erff(x*0.70710678118654752440f)); }

DEV uint32_t pk_bf16(float a, float b){
  __hip_bfloat16 ha = __float2bfloat16(a), hb = __float2bfloat16(b);
  return (uint32_t)*reinterpret_cast<uint16_t*>(&ha)
       | ((uint32_t)*reinterpret_cast<uint16_t*>(&hb) << 16);
}

// ---------------- subject counting-sort (1 block, 1024 threads) ----------------
__global__ void sort_kernel(const int* __restrict__ ids, int* __restrict__ rowmap,
                            int* __restrict__ tileS){
  __shared__ int hist[16][4];
  __shared__ int basew[16][4];
  __shared__ int pstart[5];
  int tid = threadIdx.x;
  if (tid < MP) rowmap[tid] = -1;
  if (tid + 1024 < MP) rowmap[tid + 1024] = -1;
  int w = tid >> 6, lane = tid & 63;
  int my = ids[tid];
  unsigned long long mymask = 0ull;
  #pragma unroll
  for (int s = 0; s < 4; ++s){
    unsigned long long m = __ballot(my == s);
    if (lane == 0) hist[w][s] = (int)__popcll(m);
    if (s == my) mymask = m;
  }
  int myrank = (int)__popcll(mymask & ((1ull << lane) - 1ull));
  __syncthreads();
  if (tid == 0){
    for (int s = 0; s < 4; ++s){
      int run = 0;
      for (int ww = 0; ww < 16; ++ww){ basew[ww][s] = run; run += hist[ww][s]; }
      hist[0][s] = run;
    }
    pstart[0] = 0;
    for (int s = 0; s < 4; ++s) pstart[s+1] = pstart[s] + ((hist[0][s] + 127) & ~127);
  }
  __syncthreads();
  int pos = pstart[my] + basew[w][my] + myrank;
  rowmap[pos] = tid;
  if (tid < MT){
    int row0 = tid << 7, s = -1;
    for (int ss = 0; ss < 4; ++ss) if (row0 >= pstart[ss] && row0 < pstart[ss+1]) s = ss;
    tileS[tid] = s;
  }
}

// ---------------- gather voxels into sorted order, fp32 -> bf16 ----------------
__global__ void gather_voxels(const float* __restrict__ vox, const int* __restrict__ rowmap,
                              __hip_bfloat16* __restrict__ Vs){
  int r = blockIdx.x, tid = threadIdx.x;
  int orig = rowmap[r];
  #pragma unroll
  for (int i = 0; i < 4; ++i){
    int c = (i*256 + tid) << 2;
    float4 v = {0.f,0.f,0.f,0.f};
    if (orig >= 0) v = *reinterpret_cast<const float4*>(vox + (size_t)orig*IN + c);
    __hip_bfloat16 o[4] = {__float2bfloat16(v.x), __float2bfloat16(v.y),
                           __float2bfloat16(v.z), __float2bfloat16(v.w)};
    *reinterpret_cast<uint2*>(Vs + (size_t)r*IN + c) = *reinterpret_cast<const uint2*>(o);
  }
}

// ---------------- 128x128 tile MFMA GEMM, fused fp32->bf16 B transpose ----------------
// Decode: xcd = b&7; r = b>>3; mt = r%MT; q = r/MT; kzi = xcd/nx; nt = q*nx + xcd%nx.
// kz is CORRELATED with XCD so each XCD's L2 holds one A K-slice + its B panels.
// No atomics: split-K writes to KZ partial buffers (pstride apart); consumers sum.
enum { EPI_SPLIT = 0, EPI_RES_BF16 = 1, EPI_HEADS = 3 };

template<int EPI>
__global__ __launch_bounds__(256, 2)
void gemm_bf16(const __hip_bfloat16* __restrict__ A, int lda,
               const float* __restrict__ Bw, int ldn, long long wsub,
               const int* __restrict__ tileS, const int* __restrict__ rowmap,
               int nx, int ksplit,
               const float* __restrict__ bias, int biassub,
               const float* __restrict__ resid, int ldres,
               float* __restrict__ outf, __hip_bfloat16* __restrict__ outb, int ldo,
               size_t pstride, const float* __restrict__ Bw2)
{
  int b   = blockIdx.x;
  int xcd = b & 7;
  int r0  = b >> 3;
  int mt  = r0 % MT;
  int q   = r0 / MT;
  int kzi = xcd / nx;
  int nt  = q * nx + (xcd % nx);

  int s = tileS[mt];
  if (s < 0) return;                       // inactive (pad) row tile
  const __hip_bfloat16* Ab = A + (size_t)mt*128*lda;

  const float* Bb;
  int ntl = nt;
  if constexpr (EPI == EPI_HEADS){
    if (nt < 6){ Bb = Bw  + (size_t)nt*128; }
    else       { Bb = Bw2 + (size_t)(nt-6)*128; }
    ntl = nt;                              // col in concat [0,1536)
  } else {
    Bb = Bw + (size_t)s*wsub + (size_t)nt*128;
  }

  int kb = kzi * ksplit;
  int nk = ksplit >> 6;

  __shared__ __hip_bfloat16 sA[2][128*64];
  __shared__ __hip_bfloat16 sB[2][128*64];

  int tid = threadIdx.x;
  int lane = tid & 63;
  int wv = tid >> 6, wr = wv >> 1, wc = wv & 1;

  int kq = tid >> 5;
  int nq = tid & 31;
  int n4 = nq << 2;

  f32x4 acc[4][4];
  #pragma unroll
  for (int i = 0; i < 4; ++i)
    #pragma unroll
    for (int j = 0; j < 4; ++j) acc[i][j] = (f32x4){0.f,0.f,0.f,0.f};

  auto stageA = [&](int buf, int k0){
    #pragma unroll
    for (int i = 0; i < 4; ++i){
      int cell = i*256 + tid;
      int row = cell >> 3, cc = cell & 7;
      int kg = k0 + ((cc ^ (row & 7)) << 3);
      __builtin_amdgcn_global_load_lds(
        (const __attribute__((address_space(1))) void*)(Ab + (size_t)row*lda + kg),
        (__attribute__((address_space(3))) void*)(&sA[buf][cell<<3]), 16, 0, 0);
    }
  };

  auto stageB_load = [&](int k0g, float4* F){
    const float* p = Bb + (size_t)(k0g + (kq<<3))*ldn + n4;
    #pragma unroll
    for (int rr = 0; rr < 8; ++rr)
      F[rr] = *reinterpret_cast<const float4*>(p + (size_t)rr*ldn);
  };
  auto stageB_write = [&](int buf, const float4* F){
    #pragma unroll
    for (int j = 0; j < 4; ++j){
      int n = n4 + j;
      int cell = (kq ^ (n >> 3) ^ n) & 7;
      uint4 d;
      d.x = pk_bf16(((const float*)&F[0])[j], ((const float*)&F[1])[j]);
      d.y = pk_bf16(((const float*)&F[2])[j], ((const float*)&F[3])[j]);
      d.z = pk_bf16(((const float*)&F[4])[j], ((const float*)&F[5])[j]);
      d.w = pk_bf16(((const float*)&F[6])[j], ((const float*)&F[7])[j]);
      *reinterpret_cast<uint4*>(&sB[buf][(n<<6) + (cell<<3)]) = d;
    }
  };

  float4 F[8];
  stageB_load(kb, F);
  stageA(0, kb);
  stageB_write(0, F);
  __syncthreads();

  for (int t = 0; t < nk; ++t){
    if (t+1 < nk){
      stageB_load(kb + ((t+1)<<6), F);
      stageA((t+1)&1, kb + ((t+1)<<6));
    }
    const char* baseA = (const char*)(&sA[t&1][0]);
    const char* baseB = (const char*)(&sB[t&1][0]);
    int rA = (wr<<6) + (lane & 15);
    int rB = (wc<<6) + (lane & 15);
    #pragma unroll
    for (int kk = 0; kk < 2; ++kk){
      int koffA = ((((kk<<5) + ((lane>>4)<<3)) << 1)) ^ ((lane & 7) << 4);
      bf16x8 av[4], bv[4];
      #pragma unroll
      for (int f = 0; f < 4; ++f){
        int rowA = rA + f*16;
        av[f] = *reinterpret_cast<const bf16x8*>(baseA + (size_t)rowA*128 + koffA);
        int rowB = rB + f*16;
        int cellB = (((kk<<2) + (lane>>4)) ^ (rowB >> 3) ^ rowB) & 7;
        bv[f] = *reinterpret_cast<const bf16x8*>(baseB + (size_t)rowB*128 + (cellB<<4));
      }
      #pragma unroll
      for (int i = 0; i < 4; ++i)
        #pragma unroll
        for (int j = 0; j < 4; ++j)
          acc[i][j] = __builtin_amdgcn_mfma_f32_16x16x32_bf16(av[i], bv[j], acc[i][j], 0, 0, 0);
    }
    if (t+1 < nk) stageB_write((t+1)&1, F);
    __syncthreads();
  }

  // epilogue; C/D layout (m89-verified): col = lane&15, row = (lane>>4)*4 + reg
  #pragma unroll
  for (int i = 0; i < 4; ++i){
    int rbase = (mt<<7) + (wr<<6) + (i<<4) + ((lane>>4)<<2);
    #pragma unroll
    for (int j = 0; j < 4; ++j){
      int colp = (wc<<6) + (j<<4) + (lane & 15);
      #pragma unroll
      for (int qq = 0; qq < 4; ++qq){
        int r = rbase + qq;
        float v = acc[i][j][qq];
        if constexpr (EPI == EPI_SPLIT){
          int col = (nt<<7) + colp;
          outf[(size_t)kzi*pstride + (size_t)r*ldo + col] = v;
        } else if constexpr (EPI == EPI_RES_BF16){
          int col = (nt<<7) + colp;
          int orig = rowmap[r];
          if (orig >= 0){
            v += bias[(size_t)s*biassub + col] + resid[(size_t)orig*ldres + col];
            outb[(size_t)r*ldo + col] = __float2bfloat16(v);
          }
        } else { // EPI_HEADS: store to partial buffer (concat col space)
          int col = (ntl<<7) + colp;
          outf[(size_t)kzi*pstride + (size_t)r*ldo + col] = v;
        }
      }
    }
  }
}

// ---------------- T1 = gelu(sum_p T1p + db[s])  (bf16) ----------------
__global__ void t1_epilogue(const float* __restrict__ Tp, const float* __restrict__ db,
                            const int* __restrict__ rowmap, const int* __restrict__ tileS,
                            __hip_bfloat16* __restrict__ T1){
  int idx = blockIdx.x*256 + threadIdx.x;
  int r = idx >> 7, c = idx & 127;
  float v = 0.f;
  if (rowmap[r] >= 0){
    int s = tileS[r >> 7];
    float acc = 0.f;
    #pragma unroll
    for (int p = 0; p < 8; ++p) acc += Tp[(size_t)p*MP*BOT + idx];
    v = gelu_exact(acc + db[s*BOT + c]);
  }
  T1[idx] = __float2bfloat16(v);
}

// ---------------- row LN over summed partials (+linear bias) + gelu (+residual) ------
template<int RES, int NPART>
__global__ void ln_gelu_kernel(const float* __restrict__ Zp, size_t pstride,
                               const float* __restrict__ g,
                               const float* __restrict__ b, int gsub,
                               const float* __restrict__ lb,
                               const int* __restrict__ tileS, const int* __restrict__ rowmap,
                               float* __restrict__ Xf, __hip_bfloat16* __restrict__ Xb){
  int r = blockIdx.x, tid = threadIdx.x;
  size_t rowoff = (size_t)r * H;
  int c0 = tid << 3;
  int orig = rowmap[r];
  if (orig < 0){
    float4 zf = {0.f,0.f,0.f,0.f};
    *reinterpret_cast<float4*>(Xf + rowoff + c0)     = zf;
    *reinterpret_cast<float4*>(Xf + rowoff + c0 + 4) = zf;
    uint4 zu = {0u,0u,0u,0u};
    *reinterpret_cast<uint4*>(Xb + rowoff + c0) = zu;
    return;
  }
  int si = gsub ? tileS[r>>7] : 0;
  const float* gp  = g  + (size_t)si*gsub;
  const float* bp  = b  + (size_t)si*gsub;
  const float* lbp = lb + (size_t)si*gsub;
  float z[8];
  #pragma unroll
  for (int j = 0; j < 8; ++j) z[j] = lbp[c0+j];
  #pragma unroll
  for (int p = 0; p < NPART; ++p){
    float4 v1 = *reinterpret_cast<const float4*>(Zp + p*pstride + rowoff + c0);
    float4 v2 = *reinterpret_cast<const float4*>(Zp + p*pstride + rowoff + c0 + 4);
    z[0]+=v1.x; z[1]+=v1.y; z[2]+=v1.z; z[3]+=v1.w;
    z[4]+=v2.x; z[5]+=v2.y; z[6]+=v2.z; z[7]+=v2.w;
  }
  float s1 = 0.f, s2 = 0.f;
  #pragma unroll
  for (int j = 0; j < 8; ++j){ s1 += z[j]; s2 += z[j]*z[j]; }
  #pragma unroll
  for (int m = 32; m >= 1; m >>= 1){ s1 += __shfl_xor(s1, m); s2 += __shfl_xor(s2, m); }
  __shared__ float red[4][2];
  int wv = tid >> 6, lane = tid & 63;
  if (lane == 0){ red[wv][0] = s1; red[wv][1] = s2; }
  __syncthreads();
  s1 = red[0][0]+red[1][0]+red[2][0]+red[3][0];
  s2 = red[0][1]+red[1][1]+red[2][1]+red[3][1];
  const float invH = 1.f / (float)H;
  float mu  = s1 * invH;
  float var = s2 * invH - mu*mu;
  float rs  = rsqrtf(var + 1e-5f);
  float o[8];
  #pragma unroll
  for (int j = 0; j < 8; ++j){
    float t = (z[j]-mu)*rs*gp[c0+j] + bp[c0+j];
    o[j] = gelu_exact(t);
  }
  if constexpr (RES){
    float4 x1 = *reinterpret_cast<const float4*>(Xf + rowoff + c0);
    float4 x2 = *reinterpret_cast<const float4*>(Xf + rowoff + c0 + 4);
    o[0]+=x1.x; o[1]+=x1.y; o[2]+=x1.z; o[3]+=x1.w;
    o[4]+=x2.x; o[5]+=x2.y; o[6]+=x2.z; o[7]+=x2.w;
  }
  float4 w1 = {o[0],o[1],o[2],o[3]}, w2 = {o[4],o[5],o[6],o[7]};
  *reinterpret_cast<float4*>(Xf + rowoff + c0)     = w1;
  *reinterpret_cast<float4*>(Xf + rowoff + c0 + 4) = w2;
  __hip_bfloat16 ob[8];
  #pragma unroll
  for (int j = 0; j < 8; ++j) ob[j] = __float2bfloat16(o[j]);
  *reinterpret_cast<uint4*>(Xb + rowoff + c0) = *reinterpret_cast<const uint4*>(ob);
}

// ---------------- heads combine: sum 2 partials + bias, scatter to original rows ------
__global__ void head_combine(const float* __restrict__ Hp, size_t pstride,
                             const float* __restrict__ img_b, const float* __restrict__ txt_b,
                             const int* __restrict__ rowmap,
                             float* __restrict__ oimg, float* __restrict__ otxt){
  int r = blockIdx.x;
  int orig = rowmap[r];
  if (orig < 0) return;
  int col = threadIdx.x << 2;                    // 384 threads x 4 cols = 1536
  size_t base = (size_t)r*(IMG+TXT) + col;
  float4 v0 = *reinterpret_cast<const float4*>(Hp + base);
  float4 v1 = *reinterpret_cast<const float4*>(Hp + pstride + base);
  float4 bb = (col < IMG)
            ? *reinterpret_cast<const float4*>(img_b + col)
            : *reinterpret_cast<const float4*>(txt_b + (col - IMG));
  float4 o = {v0.x+v1.x+bb.x, v0.y+v1.y+bb.y, v0.z+v1.z+bb.z, v0.w+v1.w+bb.w};
  if (col < IMG) *reinterpret_cast<float4*>(oimg + (size_t)orig*IMG + col) = o;
  else           *reinterpret_cast<float4*>(otxt + (size_t)orig*TXT + (col-IMG)) = o;
}

// ------------------------------------------------------------------------------
extern "C" void kernel_launch(void* const* d_in, const int* in_sizes, int n_in,
                              void* d_out, int out_size, void* d_ws, size_t ws_size,
                              hipStream_t stream){
  (void)in_sizes; (void)n_in; (void)out_size; (void)ws_size;
  const float* vox       = (const float*)d_in[0];
  const int*   ids       = (const int*)  d_in[1];
  const float* ad_down_w = (const float*)d_in[2];
  const float* ad_down_b = (const float*)d_in[3];
  const float* ad_up_w   = (const float*)d_in[4];
  const float* ad_up_b   = (const float*)d_in[5];
  const float* enc_w     = (const float*)d_in[6];
  const float* enc_b     = (const float*)d_in[7];
  const float* enc_ln_g  = (const float*)d_in[8];
  const float* enc_ln_bb = (const float*)d_in[9];
  const float* bb_w      = (const float*)d_in[10];
  const float* bb_b      = (const float*)d_in[11];
  const float* bb_ln_g   = (const float*)d_in[12];
  const float* bb_ln_b   = (const float*)d_in[13];
  const float* img_w     = (const float*)d_in[14];
  const float* img_b     = (const float*)d_in[15];
  const float* txt_w     = (const float*)d_in[16];
  const float* txt_b     = (const float*)d_in[17];
  float* out = (float*)d_out;

  char* wp = (char*)d_ws;
  auto alloc = [&](size_t bytes)->char*{ char* p = wp; wp += (bytes + 255) & ~(size_t)255; return p; };
  int* rowmap = (int*)alloc(MP * sizeof(int));
  int* tileS  = (int*)alloc(MT * sizeof(int));
  __hip_bfloat16* Vs    = (__hip_bfloat16*)alloc((size_t)MP*IN*2);
  float* T1p            = (float*)alloc((size_t)8*MP*BOT*4);
  __hip_bfloat16* T1    = (__hip_bfloat16*)alloc((size_t)MP*BOT*2);
  __hip_bfloat16* Hs    = (__hip_bfloat16*)alloc((size_t)MP*IN*2);
  float* Zp             = (float*)alloc((size_t)4*MP*H*4);
  float* Hp             = (float*)alloc((size_t)2*MP*(IMG+TXT)*4);
  float* Xf             = (float*)alloc((size_t)MP*H*4);
  __hip_bfloat16* Xb    = (__hip_bfloat16*)alloc((size_t)MP*H*2);

  const size_t ZPS = (size_t)MP*H;        // Z partial stride (floats)
  const size_t TPS = (size_t)MP*BOT;
  const size_t HPS = (size_t)MP*(IMG+TXT);

  sort_kernel<<<1, 1024, 0, stream>>>(ids, rowmap, tileS);
  gather_voxels<<<MP, 256, 0, stream>>>(vox, rowmap, Vs);

  // K1: adapter down, NT=1, KZ=8 (nx=1, ksplit=512) -> 8 partials
  gemm_bf16<EPI_SPLIT><<<MT*8, 256, 0, stream>>>(
      Vs, IN, ad_down_w, BOT, (long long)IN*BOT, tileS, rowmap, 1, 512,
      nullptr, 0, nullptr, 0, T1p, nullptr, BOT, TPS, nullptr);
  t1_epilogue<<<MP*BOT/256, 256, 0, stream>>>(T1p, ad_down_b, rowmap, tileS, T1);

  // K2: adapter up + residual, NT=32, KZ=1 (nx=8) -> bf16 Hs
  gemm_bf16<EPI_RES_BF16><<<MT*32, 256, 0, stream>>>(
      T1, BOT, ad_up_w, IN, (long long)BOT*IN, tileS, rowmap, 8, 128,
      ad_up_b, IN, vox, IN, nullptr, Hs, IN, 0, nullptr);

  // K3: encoder linear, NT=16, KZ=4 (nx=2, ksplit=1024) -> 4 partials; bias in LN
  gemm_bf16<EPI_SPLIT><<<MT*16*4, 256, 0, stream>>>(
      Hs, IN, enc_w, H, (long long)IN*H, tileS, rowmap, 2, 1024,
      nullptr, 0, nullptr, 0, Zp, nullptr, H, ZPS, nullptr);
  ln_gelu_kernel<0,4><<<MP, 256, 0, stream>>>(Zp, ZPS, enc_ln_g, enc_ln_bb, H, enc_b,
                                              tileS, rowmap, Xf, Xb);

  // backbone: 6 x (linear NT=16 KZ=2 (nx=4) -> 2 partials; X += gelu(ln(sum + b)))
  for (int d = 0; d < DEPTH; ++d){
    gemm_bf16<EPI_SPLIT><<<MT*16*2, 256, 0, stream>>>(
        Xb, H, bb_w + (size_t)d*H*H, H, 0, tileS, rowmap, 4, 1024,
        nullptr, 0, nullptr, 0, Zp, nullptr, H, ZPS, nullptr);
    ln_gelu_kernel<1,2><<<MP, 256, 0, stream>>>(Zp, ZPS, bb_ln_g + (size_t)d*H,
                                                bb_ln_b + (size_t)d*H, 0, bb_b + (size_t)d*H,
                                                tileS, rowmap, Xf, Xb);
  }

  // heads: ONE gemm (img cols 0..5, txt 6..11), NT=12, KZ=2 (nx=4) -> 2 partials
  gemm_bf16<EPI_HEADS><<<MT*12*2, 256, 0, stream>>>(
      Xb, H, img_w, IMG, 0, tileS, rowmap, 4, 1024,
      nullptr, 0, nullptr, 0, Hp, nullptr, IMG+TXT, HPS, txt_w);
  head_combine<<<MP, 384, 0, stream>>>(Hp, HPS, img_b, txt_b, rowmap,
                                       out, out + (size_t)BATCH*IMG);
}